// Round 1
// baseline (4175.671 us; speedup 1.0000x reference)
//
#include <hip/hip_runtime.h>
#include <cstddef>

// ---------------------------------------------------------------------------
// CustomConvLayer: watermark-modulated dynamic-filter conv network (fp32).
// Pipeline:
//  K1  wm embedding MLP -> wm_coff (32,128)
//  K2  avgpool2 + channel modulation -> t0 (32,128,64,64)
//  K3  conv 128->64 k3 s1 p0 + lrelu(.01) -> t1 (32,64,62,62)   [tiled]
//  K4  conv 64->64  k3 s2 p0 + lrelu      -> t2 (32,64,30,30)
//  K5  conv 64->64  k3 s2 p0 + lrelu      -> t3 (32,64,14,14)
//  K6  fused heads: S[576] trick, 4 agg heads + att head + katt (32,4)
//  K7  synthesize per-sample weights, fold wm_coff -> wfin (32,64,128,3,3)
//  K8  per-sample conv x(128,128x128) * wfin -> out (32,64,128,128) [tiled]
// ---------------------------------------------------------------------------

__global__ void k_wm_embed(const float* __restrict__ wm, const float* __restrict__ w1,
                           const float* __restrict__ b1, const float* __restrict__ w2,
                           const float* __restrict__ b2, float* __restrict__ coff) {
    int b = blockIdx.x;      // 32
    int j = threadIdx.x;     // 128
    __shared__ float h[128];
    float acc = b1[j];
    for (int k = 0; k < 32; ++k) acc += wm[b * 32 + k] * w1[j * 32 + k];
    h[j] = acc >= 0.f ? acc : 0.2f * acc;   // slope 0.2
    __syncthreads();
    float acc2 = b2[j];
    for (int k = 0; k < 128; ++k) acc2 += h[k] * w2[j * 128 + k];
    coff[b * 128 + j] = acc2;
}

// t0[b,c,y,x] = coff[b,c] * mean2x2(x)
__global__ __launch_bounds__(256) void k_pool_mod(const float* __restrict__ x,
                                                  const float* __restrict__ coff,
                                                  float* __restrict__ t0) {
    int idx = blockIdx.x * 256 + threadIdx.x;   // total 32*128*64*64 = 2^24
    int xo = idx & 63;
    int yo = (idx >> 6) & 63;
    int c  = (idx >> 12) & 127;
    int b  = idx >> 19;
    const float* xp = x + ((((size_t)b * 128 + c) * 128 + yo * 2) * 128 + xo * 2);
    float s = xp[0] + xp[1] + xp[128] + xp[129];
    t0[idx] = 0.25f * s * coff[b * 128 + c];
}

// Generic tiled 3x3 stride-1 conv. 16x16 spatial tile x 8 co per block,
// cin chunks of 16 staged in LDS (18x18 halo tile) + weights in LDS.
template<bool LRELU, bool PER_BATCH_W, bool HAS_BIAS>
__global__ __launch_bounds__(256) void k_conv3x3_tiled(
    const float* __restrict__ in, const float* __restrict__ w,
    const float* __restrict__ bias, float* __restrict__ out,
    int Cin, int Cout, int Hin, int Win, int Hout, int Wout, int pad, int tiles_x)
{
    __shared__ float xt[16 * 324];   // 16 cin x 18x18
    __shared__ float wt[8 * 16 * 9]; // 8 co x 16 cin x 9
    const int tid = threadIdx.x;
    const int b = blockIdx.z;
    const int co0 = blockIdx.y * 8;
    const int tile_y = (blockIdx.x / tiles_x) * 16;
    const int tile_x = (blockIdx.x % tiles_x) * 16;
    const int ty = tid >> 4, tx = tid & 15;
    const int oy = tile_y + ty, ox = tile_x + tx;
    const bool active = (oy < Hout) && (ox < Wout);
    const float* inb = in + (size_t)b * Cin * Hin * Win;
    const float* wb  = PER_BATCH_W ? (w + (size_t)b * Cout * Cin * 9) : w;

    float acc[8];
#pragma unroll
    for (int i = 0; i < 8; ++i) acc[i] = 0.f;

    for (int cc = 0; cc < Cin; cc += 16) {
        for (int i = tid; i < 16 * 324; i += 256) {
            int ci = i / 324, rem = i - ci * 324;
            int ly = rem / 18, lx = rem - ly * 18;
            int iy = tile_y + ly - pad, ix = tile_x + lx - pad;
            float v = 0.f;
            if (iy >= 0 && iy < Hin && ix >= 0 && ix < Win)
                v = inb[((size_t)(cc + ci) * Hin + iy) * Win + ix];
            xt[i] = v;
        }
        for (int i = tid; i < 1152; i += 256) {
            int coi = i / 144, rem = i - coi * 144;   // rem = ci*9 + k (contiguous)
            wt[i] = wb[((size_t)(co0 + coi) * Cin + cc) * 9 + rem];
        }
        __syncthreads();
        if (active) {
#pragma unroll 4
            for (int ci = 0; ci < 16; ++ci) {
                const float* xp = &xt[ci * 324 + ty * 18 + tx];
                float x0 = xp[0],  x1 = xp[1],  x2 = xp[2];
                float x3 = xp[18], x4 = xp[19], x5 = xp[20];
                float x6 = xp[36], x7 = xp[37], x8 = xp[38];
#pragma unroll
                for (int coi = 0; coi < 8; ++coi) {
                    const float* wp = &wt[(coi * 16 + ci) * 9];
                    acc[coi] += x0*wp[0] + x1*wp[1] + x2*wp[2]
                              + x3*wp[3] + x4*wp[4] + x5*wp[5]
                              + x6*wp[6] + x7*wp[7] + x8*wp[8];
                }
            }
        }
        __syncthreads();
    }
    if (active) {
#pragma unroll
        for (int coi = 0; coi < 8; ++coi) {
            float v = acc[coi];
            if (HAS_BIAS) v += bias[co0 + coi];
            if (LRELU) v = v >= 0.f ? v : 0.01f * v;
            out[(((size_t)b * Cout + co0 + coi) * Hout + oy) * Wout + ox] = v;
        }
    }
}

// Small 3x3 stride-2 pad-0 conv: one block per (co, b); weights for co in LDS.
template<bool LRELU>
__global__ __launch_bounds__(256) void k_conv3x3_s2(
    const float* __restrict__ in, const float* __restrict__ w,
    const float* __restrict__ bias, float* __restrict__ out,
    int Cin, int Hin, int Win, int Hout, int Wout)
{
    const int co = blockIdx.x, Cout = gridDim.x, b = blockIdx.y;
    extern __shared__ float wl[];   // Cin*9
    for (int i = threadIdx.x; i < Cin * 9; i += 256) wl[i] = w[(size_t)co * Cin * 9 + i];
    __syncthreads();
    const float* ib = in + (size_t)b * Cin * Hin * Win;
    const int npix = Hout * Wout;
    const float bv = bias[co];
    for (int p = threadIdx.x; p < npix; p += 256) {
        int oyr = p / Wout, oxr = p - oyr * Wout;
        int iy0 = oyr * 2, ix0 = oxr * 2;
        float acc = bv;
        for (int ci = 0; ci < Cin; ++ci) {
            const float* xp = ib + ((size_t)ci * Hin + iy0) * Win + ix0;
            const float* wp = wl + ci * 9;
            acc += xp[0]*wp[0] + xp[1]*wp[1] + xp[2]*wp[2]
                 + xp[Win]*wp[3] + xp[Win+1]*wp[4] + xp[Win+2]*wp[5]
                 + xp[2*Win]*wp[6] + xp[2*Win+1]*wp[7] + xp[2*Win+2]*wp[8];
        }
        out[((size_t)b * Cout + co) * npix + p] = LRELU ? (acc >= 0.f ? acc : 0.01f * acc) : acc;
    }
}

// Fused heads. Uses: mean_pos(conv) = (1/36) sum_{cin,k} w[co,cin,k]*S[cin,k]
// with S[cin,k] = sum over the 6x6 stride-2 output positions of t3.
struct HeadPtrs { const float* w[5]; const float* b[5]; };

__global__ __launch_bounds__(256) void k_heads_fused(
    const float* __restrict__ t3, HeadPtrs hp,
    const float* __restrict__ att_fw, const float* __restrict__ att_fb,
    float* __restrict__ agg, float* __restrict__ katt)
{
    int b = blockIdx.x;
    __shared__ float S[576];
    __shared__ float ah[128];
    const float* tb = t3 + (size_t)b * 64 * 196;
    for (int i = threadIdx.x; i < 576; i += 256) {
        int ci = i / 9, k = i - ci * 9, kh = k / 3, kw = k - kh * 3;
        const float* tp = tb + ci * 196 + kh * 14 + kw;
        float s = 0.f;
#pragma unroll
        for (int oy = 0; oy < 6; ++oy)
#pragma unroll
            for (int ox = 0; ox < 6; ++ox) s += tp[oy * 28 + ox * 2];
        S[i] = s;
    }
    __syncthreads();
    for (int j = threadIdx.x; j < 640; j += 256) {
        int h = j >> 7, co = j & 127;
        const float* wp = hp.w[h] + (size_t)co * 576;
        float acc = 0.f;
        for (int k = 0; k < 576; ++k) acc += wp[k] * S[k];
        float v = acc * (1.f / 36.f) + hp.b[h][co];
        if (h < 4) agg[((size_t)b * 4 + h) * 128 + co] = v;
        else       ah[co] = v >= 0.f ? v : 0.01f * v;   // lrelu(.01) before att linear
    }
    __syncthreads();
    if (threadIdx.x < 4) {
        int e = threadIdx.x;
        float acc = att_fb[e];
        for (int j = 0; j < 128; ++j) acc += ah[j] * att_fw[e * 128 + j];
        katt[b * 4 + e] = acc;
    }
}

// wfin[b,co,cin,k] = wm_coff[b,cin] * sum_e katt[b,e]*agg[b,e,cin]*expert_w[e,co,cin,k]
__global__ __launch_bounds__(256) void k_combine(
    const float* __restrict__ expert_w, const float* __restrict__ agg,
    const float* __restrict__ katt, const float* __restrict__ coff,
    float* __restrict__ wfin)
{
    int idx = blockIdx.x * 256 + threadIdx.x;   // 32*64*128*9 = 2359296 exact
    int k   = idx % 9;
    int cin = (idx / 9) & 127;
    int co  = (idx / (9 * 128)) & 63;
    int b   = idx / (9 * 128 * 64);
    float s = 0.f;
#pragma unroll
    for (int e = 0; e < 4; ++e)
        s += katt[b * 4 + e] * agg[((size_t)b * 4 + e) * 128 + cin]
           * expert_w[(((size_t)e * 64 + co) * 128 + cin) * 9 + k];
    wfin[idx] = s * coff[b * 128 + cin];
}

extern "C" void kernel_launch(void* const* d_in, const int* in_sizes, int n_in,
                              void* d_out, int out_size, void* d_ws, size_t ws_size,
                              hipStream_t stream) {
    const float* x      = (const float*)d_in[0];
    const float* wm     = (const float*)d_in[1];
    const float* wm_w1  = (const float*)d_in[2];
    const float* wm_b1  = (const float*)d_in[3];
    const float* wm_w2  = (const float*)d_in[4];
    const float* wm_b2  = (const float*)d_in[5];
    const float* tr_w1  = (const float*)d_in[6];
    const float* tr_b1  = (const float*)d_in[7];
    const float* tr_w2  = (const float*)d_in[8];
    const float* tr_b2  = (const float*)d_in[9];
    const float* tr_w3  = (const float*)d_in[10];
    const float* tr_b3  = (const float*)d_in[11];
    const float* t1_w   = (const float*)d_in[12];
    const float* t1_b   = (const float*)d_in[13];
    const float* t2_w   = (const float*)d_in[14];
    const float* t2_b   = (const float*)d_in[15];
    const float* t3_w   = (const float*)d_in[16];
    const float* t3_b   = (const float*)d_in[17];
    const float* t4_w   = (const float*)d_in[18];
    const float* t4_b   = (const float*)d_in[19];
    const float* att_cw = (const float*)d_in[20];
    const float* att_cb = (const float*)d_in[21];
    const float* att_fw = (const float*)d_in[22];
    const float* att_fb = (const float*)d_in[23];
    const float* expert_w = (const float*)d_in[24];
    float* out = (float*)d_out;

    // Workspace layout (floats)
    float* ws = (float*)d_ws;
    float* wm_coff = ws;                       // 4096
    float* agg     = ws + 4096;                // 16384
    float* katt    = ws + 20480;               // 128
    float* t0      = ws + 20608;               // 16777216  (32,128,64,64)
    float* t1      = ws + 16797824;            // 7872512   (32,64,62,62)
    float* t2      = ws + 24670336;            // 1843200   (32,64,30,30)
    float* t3      = ws + 26513536;            // 401408    (32,64,14,14)
    float* wfin    = ws + 26914944;            // 2359296   (32,64,128,3,3)
    // total 29274240 floats = ~117 MB

    // K1: watermark embedding MLP
    k_wm_embed<<<32, 128, 0, stream>>>(wm, wm_w1, wm_b1, wm_w2, wm_b2, wm_coff);

    // K2: avgpool2 + modulation
    k_pool_mod<<<65536, 256, 0, stream>>>(x, wm_coff, t0);

    // K3: tower conv1 128->64 s1 p0 (64x64 -> 62x62), lrelu
    k_conv3x3_tiled<true, false, true><<<dim3(16, 8, 32), 256, 0, stream>>>(
        t0, tr_w1, tr_b1, t1, 128, 64, 64, 64, 62, 62, 0, 4);

    // K4: conv2 64->64 s2 (62 -> 30), lrelu
    k_conv3x3_s2<true><<<dim3(64, 32), 256, 64 * 9 * 4, stream>>>(
        t1, tr_w2, tr_b2, t2, 64, 62, 62, 30, 30);

    // K5: conv3 64->64 s2 (30 -> 14), lrelu
    k_conv3x3_s2<true><<<dim3(64, 32), 256, 64 * 9 * 4, stream>>>(
        t2, tr_w3, tr_b3, t3, 64, 30, 30, 14, 14);

    // K6: fused heads (4 agg + attention -> katt)
    HeadPtrs hp;
    hp.w[0] = t1_w; hp.w[1] = t2_w; hp.w[2] = t3_w; hp.w[3] = t4_w; hp.w[4] = att_cw;
    hp.b[0] = t1_b; hp.b[1] = t2_b; hp.b[2] = t3_b; hp.b[3] = t4_b; hp.b[4] = att_cb;
    k_heads_fused<<<32, 256, 0, stream>>>(t3, hp, att_fw, att_fb, agg, katt);

    // K7: synthesize per-sample weights (wm_coff folded in)
    k_combine<<<9216, 256, 0, stream>>>(expert_w, agg, katt, wm_coff, wfin);

    // K8: per-sample final conv, pad 1 (reads RAW x; modulation lives in wfin)
    k_conv3x3_tiled<false, true, false><<<dim3(64, 8, 32), 256, 0, stream>>>(
        x, wfin, nullptr, out, 128, 64, 128, 128, 128, 128, 1, 8);
}

// Round 3
// 1199.131 us; speedup vs baseline: 3.4822x; 3.4822x over previous
//
#include <hip/hip_runtime.h>
#include <hip/hip_bf16.h>
#include <cstddef>
#include <cstdint>

typedef __bf16 bf16;
typedef __attribute__((ext_vector_type(8))) __bf16 bf16x8;
typedef __attribute__((ext_vector_type(4))) float f32x4;

// ---------------------------------------------------------------------------
// Pipeline (fp32 in/out, bf16 MFMA for the two big convs):
//  K1  wm embedding MLP -> wm_coff (32,128)                       [fp32]
//  K2  pool2x2 + modulate -> t0b NHWC bf16 (32,64,64,128)
//  Kw  tr_w1 -> w1b bf16 [9][64][128]
//  K3  MFMA conv 128->64 s1 p0 + bias + lrelu -> t1 fp32 NCHW (32,64,62,62)
//  K4  conv 64->64 s2 + lrelu -> t2 (32,64,30,30)                 [fp32]
//  K5  conv 64->64 s2 + lrelu -> t3 (32,64,14,14)                 [fp32]
//  K6  fused heads (GAP trick) -> agg (32,4,128), katt (32,4)     [fp32]
//  K7  combine + fold wm_coff -> wfinb bf16 [32][9][64][128]
//  K8  MFMA per-sample conv(raw x, wfinb) p1 -> out fp32 NCHW
// ---------------------------------------------------------------------------

__global__ void k_wm_embed(const float* __restrict__ wm, const float* __restrict__ w1,
                           const float* __restrict__ b1, const float* __restrict__ w2,
                           const float* __restrict__ b2, float* __restrict__ coff) {
    int b = blockIdx.x;      // 32
    int j = threadIdx.x;     // 128
    __shared__ float h[128];
    float acc = b1[j];
    for (int k = 0; k < 32; ++k) acc += wm[b * 32 + k] * w1[j * 32 + k];
    h[j] = acc >= 0.f ? acc : 0.2f * acc;   // slope 0.2
    __syncthreads();
    float acc2 = b2[j];
    for (int k = 0; k < 128; ++k) acc2 += h[k] * w2[j * 128 + k];
    coff[b * 128 + j] = acc2;
}

// t0b[b][y2][x2][c] = bf16( 0.25*coff[b,c]*(2x2 sum) )   (modulated, NHWC bf16)
// FIXED: cover all 128 channels (16 slots of 8), not just 0..31.
__global__ __launch_bounds__(256) void k_pool_nhwc(const float* __restrict__ x,
                                                   const float* __restrict__ coff,
                                                   bf16* __restrict__ t0b) {
    int y2 = blockIdx.x, b = blockIdx.y;
    for (int u = threadIdx.x; u < 1024; u += 256) {   // 64 x2 * 16 slots
        int x2 = u & 63, sl = u >> 6;
        bf16x8 pk;
#pragma unroll
        for (int j = 0; j < 8; ++j) {
            int c = sl * 8 + j;
            const float* p = x + (((size_t)b * 128 + c) * 128 + y2 * 2) * 128 + x2 * 2;
            float v = 0.25f * (p[0] + p[1] + p[128] + p[129]) * coff[b * 128 + c];
            pk[j] = (bf16)v;
        }
        *(bf16x8*)(t0b + ((((size_t)b * 64 + y2) * 64 + x2) << 7) + sl * 8) = pk;
    }
}

// tr_w1 [64][128][3][3] fp32 -> w1b [tap][co][cin] bf16
__global__ void k_w1b(const float* __restrict__ w, bf16* __restrict__ o) {
    int i = blockIdx.x * 256 + threadIdx.x;     // 73728
    if (i >= 73728) return;
    int cin = i & 127, t2 = i >> 7, co = t2 & 63, tap = t2 >> 6;
    o[i] = (bf16)(w[((size_t)co * 128 + cin) * 9 + tap]);
}

// ---------------------------------------------------------------------------
// MFMA implicit-GEMM 3x3 conv, Cin=128 -> Cout=64, stride 1.
// Block: 64 co x 64 pos (one output row strip). 4 waves, each 32x32 (2x2 frags).
// LDS x-tile [3][66][128] bf16, 16B-slot XOR swizzle: LDS[r][c][s'] holds
// global cin-slot (s' ^ (c&15)) -> conflict-free ds_read_b128 B-fragments.
// Weights [tap][co][cin] bf16, A-frags loaded 16B from global (L2).
// ---------------------------------------------------------------------------
template<int PAD, bool F32SRC, bool PER_BATCH_W, bool LRELU, bool HAS_BIAS, bool SWZY>
__global__ __launch_bounds__(256, 3) void k_conv_mfma(
    const void* __restrict__ src, const bf16* __restrict__ wgt,
    const float* __restrict__ bias, float* __restrict__ out,
    int H, int W, int Hout, int Wout)
{
    __shared__ bf16 xs[3 * 66 * 128];           // 50688 B
    const int tid = threadIdx.x;
    const int wid = tid >> 6, lane = tid & 63;
    const int b = blockIdx.z;
    const int x0 = blockIdx.y << 6;
    int bx = blockIdx.x;
    // XCD y-band swizzle (gridDim.x == 128 only): contiguous 16-row bands per XCD
    const int y0 = SWZY ? (((bx & 7) << 4) | (bx >> 3)) : bx;

    // ---- stage x-tile -> LDS (reg-staged, swizzled) ----
    if (F32SRC) {
        const float* sf = (const float*)src + ((size_t)b << 7) * H * W;
        for (int i = tid; i < 3 * 128 * 66; i += 256) {
            int c = i % 66;
            int t2 = i / 66;                     // r*128 + cin
            int cin = t2 & 127, r = t2 >> 7;
            int ys = y0 - PAD + r, xsrc = x0 - PAD + c;
            float v = 0.f;
            if (ys >= 0 && ys < H && xsrc >= 0 && xsrc < W)
                v = sf[((size_t)cin * H + ys) * W + xsrc];
            int sl = (cin >> 3) ^ (c & 15);
            xs[((r * 66 + c) << 7) + (sl << 3) + (cin & 7)] = (bf16)v;
        }
    } else {
        const bf16* sb = (const bf16*)src + ((size_t)b * H * W << 7);
        for (int k = tid; k < 3 * 66 * 16; k += 256) {   // 16B chunks
            int r = k / 1056;
            int rem = k - r * 1056;
            int c = rem >> 4, sp = rem & 15;
            int ys = y0 - PAD + r, xsrc = x0 - PAD + c;
            bf16x8 v = {};
            if (ys >= 0 && ys < H && xsrc >= 0 && xsrc < W)
                v = *(const bf16x8*)(sb + (((size_t)ys * W + xsrc) << 7) + ((sp ^ (c & 15)) << 3));
            *(bf16x8*)(xs + (k << 3)) = v;       // linear dest, swizzled source
        }
    }
    __syncthreads();

    // ---- K-loop: 9 taps x 4 cin-chunks, 4 MFMA each ----
    const bf16* wb = wgt + (PER_BATCH_W ? ((size_t)b * 9 * 64 * 128) : 0);
    const int co0 = (wid >> 1) << 5;             // 0 / 32
    const int p0  = (wid & 1) << 5;              // 0 / 32
    const int l15 = lane & 15, g = lane >> 4;
    const int arow0 = co0 + l15;
    const int aoff = g << 3;                     // k-subgroup offset within 32
    f32x4 acc[2][2] = {};

    for (int r = 0; r < 3; ++r) {
        for (int dx = 0; dx < 3; ++dx) {
            const bf16* wtap = wb + ((size_t)(r * 3 + dx) << 13);
            const int c0 = p0 + l15 + dx;
            const int rowbase = (r * 66 + c0) << 7;
            const int rowbase1 = (r * 66 + c0 + 16) << 7;
#pragma unroll
            for (int q = 0; q < 4; ++q) {
                bf16x8 a0 = *(const bf16x8*)(wtap + (arow0 << 7) + (q << 5) + aoff);
                bf16x8 a1 = *(const bf16x8*)(wtap + ((arow0 + 16) << 7) + (q << 5) + aoff);
                int sl = ((q << 2) + g) ^ (c0 & 15);
                bf16x8 b0 = *(const bf16x8*)(xs + rowbase + (sl << 3));
                bf16x8 b1 = *(const bf16x8*)(xs + rowbase1 + (sl << 3));
                acc[0][0] = __builtin_amdgcn_mfma_f32_16x16x32_bf16(a0, b0, acc[0][0], 0, 0, 0);
                acc[0][1] = __builtin_amdgcn_mfma_f32_16x16x32_bf16(a0, b1, acc[0][1], 0, 0, 0);
                acc[1][0] = __builtin_amdgcn_mfma_f32_16x16x32_bf16(a1, b0, acc[1][0], 0, 0, 0);
                acc[1][1] = __builtin_amdgcn_mfma_f32_16x16x32_bf16(a1, b1, acc[1][1], 0, 0, 0);
            }
        }
    }

    // ---- epilogue: C[row=co][col=pos], col=lane&15, row=(lane>>4)*4+reg ----
#pragma unroll
    for (int m = 0; m < 2; ++m) {
#pragma unroll
        for (int n = 0; n < 2; ++n) {
            int xg = x0 + p0 + n * 16 + l15;
            if (xg < Wout) {
#pragma unroll
                for (int reg = 0; reg < 4; ++reg) {
                    int co = co0 + m * 16 + (g << 2) + reg;
                    float v = acc[m][n][reg];
                    if (HAS_BIAS) v += bias[co];
                    if (LRELU) v = v >= 0.f ? v : 0.01f * v;
                    out[(((size_t)b * 64 + co) * Hout + y0) * Wout + xg] = v;
                }
            }
        }
    }
}

// Small 3x3 stride-2 pad-0 fp32 conv: one block per (co, b); weights in LDS.
template<bool LRELU>
__global__ __launch_bounds__(256) void k_conv3x3_s2(
    const float* __restrict__ in, const float* __restrict__ w,
    const float* __restrict__ bias, float* __restrict__ out,
    int Cin, int Hin, int Win, int Hout, int Wout)
{
    const int co = blockIdx.x, Cout = gridDim.x, b = blockIdx.y;
    extern __shared__ float wl[];   // Cin*9
    for (int i = threadIdx.x; i < Cin * 9; i += 256) wl[i] = w[(size_t)co * Cin * 9 + i];
    __syncthreads();
    const float* ib = in + (size_t)b * Cin * Hin * Win;
    const int npix = Hout * Wout;
    const float bv = bias[co];
    for (int p = threadIdx.x; p < npix; p += 256) {
        int oyr = p / Wout, oxr = p - oyr * Wout;
        int iy0 = oyr * 2, ix0 = oxr * 2;
        float acc = bv;
        for (int ci = 0; ci < Cin; ++ci) {
            const float* xp = ib + ((size_t)ci * Hin + iy0) * Win + ix0;
            const float* wp = wl + ci * 9;
            acc += xp[0]*wp[0] + xp[1]*wp[1] + xp[2]*wp[2]
                 + xp[Win]*wp[3] + xp[Win+1]*wp[4] + xp[Win+2]*wp[5]
                 + xp[2*Win]*wp[6] + xp[2*Win+1]*wp[7] + xp[2*Win+2]*wp[8];
        }
        out[((size_t)b * Cout + co) * npix + p] = LRELU ? (acc >= 0.f ? acc : 0.01f * acc) : acc;
    }
}

// Fused heads: mean_pos(conv(t,w)) = (1/36) sum_{cin,k} w[co,cin,k]*S[cin,k]
struct HeadPtrs { const float* w[5]; const float* b[5]; };

__global__ __launch_bounds__(256) void k_heads_fused(
    const float* __restrict__ t3, HeadPtrs hp,
    const float* __restrict__ att_fw, const float* __restrict__ att_fb,
    float* __restrict__ agg, float* __restrict__ katt)
{
    int b = blockIdx.x;
    __shared__ float S[576];
    __shared__ float ah[128];
    const float* tb = t3 + (size_t)b * 64 * 196;
    for (int i = threadIdx.x; i < 576; i += 256) {
        int ci = i / 9, k = i - ci * 9, kh = k / 3, kw = k - kh * 3;
        const float* tp = tb + ci * 196 + kh * 14 + kw;
        float s = 0.f;
#pragma unroll
        for (int oy = 0; oy < 6; ++oy)
#pragma unroll
            for (int ox = 0; ox < 6; ++ox) s += tp[oy * 28 + ox * 2];
        S[i] = s;
    }
    __syncthreads();
    for (int j = threadIdx.x; j < 640; j += 256) {
        int h = j >> 7, co = j & 127;
        const float* wp = hp.w[h] + (size_t)co * 576;
        float acc = 0.f;
        for (int k = 0; k < 576; ++k) acc += wp[k] * S[k];
        float v = acc * (1.f / 36.f) + hp.b[h][co];
        if (h < 4) agg[((size_t)b * 4 + h) * 128 + co] = v;
        else       ah[co] = v >= 0.f ? v : 0.01f * v;
    }
    __syncthreads();
    if (threadIdx.x < 4) {
        int e = threadIdx.x;
        float acc = att_fb[e];
        for (int j = 0; j < 128; ++j) acc += ah[j] * att_fw[e * 128 + j];
        katt[b * 4 + e] = acc;
    }
}

// wfinb[b][tap][co][cin] = bf16( coff[b,cin] * sum_e katt[b,e]*agg[b,e,cin]*expert_w[e,co,cin,tap] )
__global__ __launch_bounds__(256) void k_combine(
    const float* __restrict__ expert_w, const float* __restrict__ agg,
    const float* __restrict__ katt, const float* __restrict__ coff,
    bf16* __restrict__ wfinb)
{
    int i = blockIdx.x * 256 + threadIdx.x;   // 32*9*64*128 = 2359296 exact
    int cin = i & 127;
    int co  = (i >> 7) & 63;
    int tap = (i >> 13) % 9;
    int b   = i / (9 << 13);
    float s = 0.f;
#pragma unroll
    for (int e = 0; e < 4; ++e)
        s += katt[b * 4 + e] * agg[((size_t)b * 4 + e) * 128 + cin]
           * expert_w[(((size_t)e * 64 + co) * 128 + cin) * 9 + tap];
    wfinb[i] = (bf16)(s * coff[b * 128 + cin]);
}

extern "C" void kernel_launch(void* const* d_in, const int* in_sizes, int n_in,
                              void* d_out, int out_size, void* d_ws, size_t ws_size,
                              hipStream_t stream) {
    const float* x      = (const float*)d_in[0];
    const float* wm     = (const float*)d_in[1];
    const float* wm_w1  = (const float*)d_in[2];
    const float* wm_b1  = (const float*)d_in[3];
    const float* wm_w2  = (const float*)d_in[4];
    const float* wm_b2  = (const float*)d_in[5];
    const float* tr_w1  = (const float*)d_in[6];
    const float* tr_b1  = (const float*)d_in[7];
    const float* tr_w2  = (const float*)d_in[8];
    const float* tr_b2  = (const float*)d_in[9];
    const float* tr_w3  = (const float*)d_in[10];
    const float* tr_b3  = (const float*)d_in[11];
    const float* t1_w   = (const float*)d_in[12];
    const float* t1_b   = (const float*)d_in[13];
    const float* t2_w   = (const float*)d_in[14];
    const float* t2_b   = (const float*)d_in[15];
    const float* t3_w   = (const float*)d_in[16];
    const float* t3_b   = (const float*)d_in[17];
    const float* t4_w   = (const float*)d_in[18];
    const float* t4_b   = (const float*)d_in[19];
    const float* att_cw = (const float*)d_in[20];
    const float* att_cb = (const float*)d_in[21];
    const float* att_fw = (const float*)d_in[22];
    const float* att_fb = (const float*)d_in[23];
    const float* expert_w = (const float*)d_in[24];
    float* out = (float*)d_out;

    // Workspace layout (float offsets; all 16B-aligned)
    float* ws = (float*)d_ws;
    float* wm_coff = ws;                       // 4096
    float* agg     = ws + 4096;                // 16384
    float* katt    = ws + 20480;               // 128
    bf16*  w1b     = (bf16*)(ws + 20736);      // 73728 bf16 -> 36864 f
    bf16*  wfinb   = (bf16*)(ws + 57600);      // 2359296 bf16 -> 1179648 f
    bf16*  t0b     = (bf16*)(ws + 1237248);    // 16777216 bf16 -> 8388608 f
    float* t1      = ws + 9625856;             // 7872512   (32,64,62,62)
    float* t2      = ws + 17498368;            // 1843200   (32,64,30,30)
    float* t3      = ws + 19341568;            // 401408    (32,64,14,14)
    // total ~19.75M floats = 79 MB

    // K1: watermark embedding MLP
    k_wm_embed<<<32, 128, 0, stream>>>(wm, wm_w1, wm_b1, wm_w2, wm_b2, wm_coff);

    // K2: pool + modulate -> NHWC bf16
    k_pool_nhwc<<<dim3(64, 32), 256, 0, stream>>>(x, wm_coff, t0b);

    // Kw: tower conv1 weights -> bf16 [tap][co][cin]
    k_w1b<<<288, 256, 0, stream>>>(tr_w1, w1b);

    // K3: MFMA conv1 128->64 s1 p0 (64x64 -> 62x62), bias+lrelu, fp32 NCHW out
    k_conv_mfma<0, false, false, true, true, false><<<dim3(62, 1, 32), 256, 0, stream>>>(
        (const void*)t0b, w1b, tr_b1, t1, 64, 64, 62, 62);

    // K4: conv2 64->64 s2 (62 -> 30), lrelu
    k_conv3x3_s2<true><<<dim3(64, 32), 256, 64 * 9 * 4, stream>>>(
        t1, tr_w2, tr_b2, t2, 64, 62, 62, 30, 30);

    // K5: conv3 64->64 s2 (30 -> 14), lrelu
    k_conv3x3_s2<true><<<dim3(64, 32), 256, 64 * 9 * 4, stream>>>(
        t2, tr_w3, tr_b3, t3, 64, 30, 30, 14, 14);

    // K6: fused heads
    HeadPtrs hp;
    hp.w[0] = t1_w; hp.w[1] = t2_w; hp.w[2] = t3_w; hp.w[3] = t4_w; hp.w[4] = att_cw;
    hp.b[0] = t1_b; hp.b[1] = t2_b; hp.b[2] = t3_b; hp.b[3] = t4_b; hp.b[4] = att_cb;
    k_heads_fused<<<32, 256, 0, stream>>>(t3, hp, att_fw, att_fb, agg, katt);

    // K7: synthesize per-sample bf16 weights [b][tap][co][cin], wm_coff folded
    k_combine<<<9216, 256, 0, stream>>>(expert_w, agg, katt, wm_coff, wfinb);

    // K8: MFMA per-sample conv on RAW x, pad 1, y-band XCD swizzle
    k_conv_mfma<1, true, true, false, false, true><<<dim3(128, 2, 32), 256, 0, stream>>>(
        (const void*)x, wfinb, nullptr, out, 128, 128, 128, 128);
}

// Round 4
// 943.718 us; speedup vs baseline: 4.4247x; 1.2706x over previous
//
#include <hip/hip_runtime.h>
#include <hip/hip_bf16.h>
#include <cstddef>
#include <cstdint>

typedef __bf16 bf16;
typedef __attribute__((ext_vector_type(8))) __bf16 bf16x8;
typedef __attribute__((ext_vector_type(4))) float f32x4;

// ---------------------------------------------------------------------------
// Pipeline (fp32 in/out, bf16 MFMA for the two big convs):
//  K1  wm embedding MLP -> wm_coff (32,128)                       [fp32]
//  K2  pool2x2 + modulate -> t0b NHWC bf16 (32,64,64,128)
//  Kw  tr_w1 -> w1b bf16 [9][64][128]
//  K3  MFMA conv 128->64 s1 p0 + bias + lrelu -> t1 fp32 NCHW (32,64,62,62)
//  K4  conv 64->64 s2 + lrelu -> t2 (32,64,30,30)                 [fp32]
//  K5  conv 64->64 s2 + lrelu -> t3 (32,64,14,14)                 [fp32]
//  K6  fused heads (GAP trick) -> agg (32,4,128), katt (32,4)     [fp32]
//  K7  combine + fold wm_coff -> wfinb bf16 [32][9][64][128]
//  K8  MFMA per-sample conv(raw x, wfinb) p1 -> out fp32 NCHW
// ---------------------------------------------------------------------------

__global__ void k_wm_embed(const float* __restrict__ wm, const float* __restrict__ w1,
                           const float* __restrict__ b1, const float* __restrict__ w2,
                           const float* __restrict__ b2, float* __restrict__ coff) {
    int b = blockIdx.x;      // 32
    int j = threadIdx.x;     // 128
    __shared__ float h[128];
    float acc = b1[j];
    for (int k = 0; k < 32; ++k) acc += wm[b * 32 + k] * w1[j * 32 + k];
    h[j] = acc >= 0.f ? acc : 0.2f * acc;   // slope 0.2
    __syncthreads();
    float acc2 = b2[j];
    for (int k = 0; k < 128; ++k) acc2 += h[k] * w2[j * 128 + k];
    coff[b * 128 + j] = acc2;
}

// t0b[b][y2][x2][c] = bf16( 0.25*coff[b,c]*(2x2 sum) )   (modulated, NHWC bf16)
__global__ __launch_bounds__(256) void k_pool_nhwc(const float* __restrict__ x,
                                                   const float* __restrict__ coff,
                                                   bf16* __restrict__ t0b) {
    int y2 = blockIdx.x, b = blockIdx.y;
    for (int u = threadIdx.x; u < 1024; u += 256) {   // 64 x2 * 16 slots
        int x2 = u & 63, sl = u >> 6;
        bf16x8 pk;
#pragma unroll
        for (int j = 0; j < 8; ++j) {
            int c = sl * 8 + j;
            const float* p = x + (((size_t)b * 128 + c) * 128 + y2 * 2) * 128 + x2 * 2;
            float v = 0.25f * (p[0] + p[1] + p[128] + p[129]) * coff[b * 128 + c];
            pk[j] = (bf16)v;
        }
        *(bf16x8*)(t0b + ((((size_t)b * 64 + y2) * 64 + x2) << 7) + sl * 8) = pk;
    }
}

// tr_w1 [64][128][3][3] fp32 -> w1b [tap][co][cin] bf16
__global__ void k_w1b(const float* __restrict__ w, bf16* __restrict__ o) {
    int i = blockIdx.x * 256 + threadIdx.x;     // 73728
    if (i >= 73728) return;
    int cin = i & 127, t2 = i >> 7, co = t2 & 63, tap = t2 >> 6;
    o[i] = (bf16)(w[((size_t)co * 128 + cin) * 9 + tap]);
}

// ---------------------------------------------------------------------------
// MFMA implicit-GEMM 3x3 conv, Cin=128 -> Cout=64, stride 1.
// Block: 64 co x 64 pos (one output row strip). 4 waves, each 32x32 (2x2 frags).
// LDS x-tile [3][66][128] bf16, 16B-slot XOR swizzle: LDS[r][c][s'] holds
// global cin-slot (s' ^ (c&15)) -> conflict-free ds_read_b128 B-fragments.
// Weights [tap][co][cin] bf16, A-frags loaded 16B from global (L2).
// F32SRC staging: aligned float4 global loads (coalesced), swizzled scalar LDS
// writes (bank-spread via the sl XOR). NOTE: F32SRC path assumes PAD==1, W%4==0.
// ---------------------------------------------------------------------------
template<int PAD, bool F32SRC, bool PER_BATCH_W, bool LRELU, bool HAS_BIAS, bool SWZY>
__global__ __launch_bounds__(256, 3) void k_conv_mfma(
    const void* __restrict__ src, const bf16* __restrict__ wgt,
    const float* __restrict__ bias, float* __restrict__ out,
    int H, int W, int Hout, int Wout)
{
    __shared__ bf16 xs[3 * 66 * 128];           // 50688 B
    const int tid = threadIdx.x;
    const int wid = tid >> 6, lane = tid & 63;
    const int b = blockIdx.z;
    const int x0 = blockIdx.y << 6;
    int bx = blockIdx.x;
    // XCD y-band swizzle (gridDim.x == 128 only): contiguous 16-row bands per XCD
    const int y0 = SWZY ? (((bx & 7) << 4) | (bx >> 3)) : bx;

    // ---- stage x-tile -> LDS ----
    if (F32SRC) {
        const float* sf = (const float*)src + ((size_t)b << 7) * H * W;
        // 3 r x 128 cin x 18 col-groups of 4 (aligned float4, halo folded): 6912 chunks
        for (int k = tid; k < 3 * 128 * 18; k += 256) {
            int gi = k % 18;
            int t2 = k / 18;                    // r*128 + cin
            int cin = t2 & 127, r = t2 >> 7;
            int ys = y0 - PAD + r;
            int xg = x0 - 4 + (gi << 2);        // aligned group start in source x
            f32x4 v = {0.f, 0.f, 0.f, 0.f};
            if (ys >= 0 && ys < H && xg >= 0 && xg + 3 < W)
                v = *(const f32x4*)(sf + ((size_t)cin * H + ys) * W + xg);
#pragma unroll
            for (int j = 0; j < 4; ++j) {
                int c = xg + j - x0 + PAD;      // tile column
                if (c >= 0 && c < 66) {
                    int sl = (cin >> 3) ^ (c & 15);
                    xs[((r * 66 + c) << 7) + (sl << 3) + (cin & 7)] = (bf16)v[j];
                }
            }
        }
    } else {
        const bf16* sb = (const bf16*)src + ((size_t)b * H * W << 7);
        for (int k = tid; k < 3 * 66 * 16; k += 256) {   // 16B chunks
            int r = k / 1056;
            int rem = k - r * 1056;
            int c = rem >> 4, sp = rem & 15;
            int ys = y0 - PAD + r, xsrc = x0 - PAD + c;
            bf16x8 v = {};
            if (ys >= 0 && ys < H && xsrc >= 0 && xsrc < W)
                v = *(const bf16x8*)(sb + (((size_t)ys * W + xsrc) << 7) + ((sp ^ (c & 15)) << 3));
            *(bf16x8*)(xs + (k << 3)) = v;       // linear dest, swizzled source
        }
    }
    __syncthreads();

    // ---- K-loop: 9 taps x 4 cin-chunks, 4 MFMA each ----
    const bf16* wb = wgt + (PER_BATCH_W ? ((size_t)b * 9 * 64 * 128) : 0);
    const int co0 = (wid >> 1) << 5;             // 0 / 32
    const int p0  = (wid & 1) << 5;              // 0 / 32
    const int l15 = lane & 15, g = lane >> 4;
    const int arow0 = co0 + l15;
    const int aoff = g << 3;                     // k-subgroup offset within 32
    f32x4 acc[2][2] = {};

    for (int r = 0; r < 3; ++r) {
#pragma unroll
        for (int dx = 0; dx < 3; ++dx) {
            const bf16* wtap = wb + ((size_t)(r * 3 + dx) << 13);
            const int c0 = p0 + l15 + dx;
            const int rowbase = (r * 66 + c0) << 7;
            const int rowbase1 = (r * 66 + c0 + 16) << 7;
#pragma unroll
            for (int q = 0; q < 4; ++q) {
                bf16x8 a0 = *(const bf16x8*)(wtap + (arow0 << 7) + (q << 5) + aoff);
                bf16x8 a1 = *(const bf16x8*)(wtap + ((arow0 + 16) << 7) + (q << 5) + aoff);
                int sl = ((q << 2) + g) ^ (c0 & 15);
                bf16x8 b0 = *(const bf16x8*)(xs + rowbase + (sl << 3));
                bf16x8 b1 = *(const bf16x8*)(xs + rowbase1 + (sl << 3));
                acc[0][0] = __builtin_amdgcn_mfma_f32_16x16x32_bf16(a0, b0, acc[0][0], 0, 0, 0);
                acc[0][1] = __builtin_amdgcn_mfma_f32_16x16x32_bf16(a0, b1, acc[0][1], 0, 0, 0);
                acc[1][0] = __builtin_amdgcn_mfma_f32_16x16x32_bf16(a1, b0, acc[1][0], 0, 0, 0);
                acc[1][1] = __builtin_amdgcn_mfma_f32_16x16x32_bf16(a1, b1, acc[1][1], 0, 0, 0);
            }
        }
    }

    // ---- epilogue: C[row=co][col=pos], col=lane&15, row=(lane>>4)*4+reg ----
#pragma unroll
    for (int m = 0; m < 2; ++m) {
#pragma unroll
        for (int n = 0; n < 2; ++n) {
            int xg = x0 + p0 + n * 16 + l15;
            if (xg < Wout) {
#pragma unroll
                for (int reg = 0; reg < 4; ++reg) {
                    int co = co0 + m * 16 + (g << 2) + reg;
                    float v = acc[m][n][reg];
                    if (HAS_BIAS) v += bias[co];
                    if (LRELU) v = v >= 0.f ? v : 0.01f * v;
                    out[(((size_t)b * 64 + co) * Hout + y0) * Wout + xg] = v;
                }
            }
        }
    }
}

// Small 3x3 stride-2 pad-0 fp32 conv: one block per (co, b); weights in LDS.
template<bool LRELU>
__global__ __launch_bounds__(256) void k_conv3x3_s2(
    const float* __restrict__ in, const float* __restrict__ w,
    const float* __restrict__ bias, float* __restrict__ out,
    int Cin, int Hin, int Win, int Hout, int Wout)
{
    const int co = blockIdx.x, Cout = gridDim.x, b = blockIdx.y;
    extern __shared__ float wl[];   // Cin*9
    for (int i = threadIdx.x; i < Cin * 9; i += 256) wl[i] = w[(size_t)co * Cin * 9 + i];
    __syncthreads();
    const float* ib = in + (size_t)b * Cin * Hin * Win;
    const int npix = Hout * Wout;
    const float bv = bias[co];
    for (int p = threadIdx.x; p < npix; p += 256) {
        int oyr = p / Wout, oxr = p - oyr * Wout;
        int iy0 = oyr * 2, ix0 = oxr * 2;
        float acc = bv;
        for (int ci = 0; ci < Cin; ++ci) {
            const float* xp = ib + ((size_t)ci * Hin + iy0) * Win + ix0;
            const float* wp = wl + ci * 9;
            acc += xp[0]*wp[0] + xp[1]*wp[1] + xp[2]*wp[2]
                 + xp[Win]*wp[3] + xp[Win+1]*wp[4] + xp[Win+2]*wp[5]
                 + xp[2*Win]*wp[6] + xp[2*Win+1]*wp[7] + xp[2*Win+2]*wp[8];
        }
        out[((size_t)b * Cout + co) * npix + p] = LRELU ? (acc >= 0.f ? acc : 0.01f * acc) : acc;
    }
}

// Fused heads: mean_pos(conv(t,w)) = (1/36) sum_{cin,k} w[co,cin,k]*S[cin,k]
struct HeadPtrs { const float* w[5]; const float* b[5]; };

__global__ __launch_bounds__(256) void k_heads_fused(
    const float* __restrict__ t3, HeadPtrs hp,
    const float* __restrict__ att_fw, const float* __restrict__ att_fb,
    float* __restrict__ agg, float* __restrict__ katt)
{
    int b = blockIdx.x;
    __shared__ float S[576];
    __shared__ float ah[128];
    const float* tb = t3 + (size_t)b * 64 * 196;
    for (int i = threadIdx.x; i < 576; i += 256) {
        int ci = i / 9, k = i - ci * 9, kh = k / 3, kw = k - kh * 3;
        const float* tp = tb + ci * 196 + kh * 14 + kw;
        float s = 0.f;
#pragma unroll
        for (int oy = 0; oy < 6; ++oy)
#pragma unroll
            for (int ox = 0; ox < 6; ++ox) s += tp[oy * 28 + ox * 2];
        S[i] = s;
    }
    __syncthreads();
    for (int j = threadIdx.x; j < 640; j += 256) {
        int h = j >> 7, co = j & 127;
        const float* wp = hp.w[h] + (size_t)co * 576;
        float acc = 0.f;
        for (int k = 0; k < 576; ++k) acc += wp[k] * S[k];
        float v = acc * (1.f / 36.f) + hp.b[h][co];
        if (h < 4) agg[((size_t)b * 4 + h) * 128 + co] = v;
        else       ah[co] = v >= 0.f ? v : 0.01f * v;
    }
    __syncthreads();
    if (threadIdx.x < 4) {
        int e = threadIdx.x;
        float acc = att_fb[e];
        for (int j = 0; j < 128; ++j) acc += ah[j] * att_fw[e * 128 + j];
        katt[b * 4 + e] = acc;
    }
}

// wfinb[b][tap][co][cin] = bf16( coff[b,cin] * sum_e katt[b,e]*agg[b,e,cin]*expert_w[e,co,cin,tap] )
__global__ __launch_bounds__(256) void k_combine(
    const float* __restrict__ expert_w, const float* __restrict__ agg,
    const float* __restrict__ katt, const float* __restrict__ coff,
    bf16* __restrict__ wfinb)
{
    int i = blockIdx.x * 256 + threadIdx.x;   // 32*9*64*128 = 2359296 exact
    int cin = i & 127;
    int co  = (i >> 7) & 63;
    int tap = (i >> 13) % 9;
    int b   = i / (9 << 13);
    float s = 0.f;
#pragma unroll
    for (int e = 0; e < 4; ++e)
        s += katt[b * 4 + e] * agg[((size_t)b * 4 + e) * 128 + cin]
           * expert_w[(((size_t)e * 64 + co) * 128 + cin) * 9 + tap];
    wfinb[i] = (bf16)(s * coff[b * 128 + cin]);
}

extern "C" void kernel_launch(void* const* d_in, const int* in_sizes, int n_in,
                              void* d_out, int out_size, void* d_ws, size_t ws_size,
                              hipStream_t stream) {
    const float* x      = (const float*)d_in[0];
    const float* wm     = (const float*)d_in[1];
    const float* wm_w1  = (const float*)d_in[2];
    const float* wm_b1  = (const float*)d_in[3];
    const float* wm_w2  = (const float*)d_in[4];
    const float* wm_b2  = (const float*)d_in[5];
    const float* tr_w1  = (const float*)d_in[6];
    const float* tr_b1  = (const float*)d_in[7];
    const float* tr_w2  = (const float*)d_in[8];
    const float* tr_b2  = (const float*)d_in[9];
    const float* tr_w3  = (const float*)d_in[10];
    const float* tr_b3  = (const float*)d_in[11];
    const float* t1_w   = (const float*)d_in[12];
    const float* t1_b   = (const float*)d_in[13];
    const float* t2_w   = (const float*)d_in[14];
    const float* t2_b   = (const float*)d_in[15];
    const float* t3_w   = (const float*)d_in[16];
    const float* t3_b   = (const float*)d_in[17];
    const float* t4_w   = (const float*)d_in[18];
    const float* t4_b   = (const float*)d_in[19];
    const float* att_cw = (const float*)d_in[20];
    const float* att_cb = (const float*)d_in[21];
    const float* att_fw = (const float*)d_in[22];
    const float* att_fb = (const float*)d_in[23];
    const float* expert_w = (const float*)d_in[24];
    float* out = (float*)d_out;

    // Workspace layout (float offsets; all 16B-aligned)
    float* ws = (float*)d_ws;
    float* wm_coff = ws;                       // 4096
    float* agg     = ws + 4096;                // 16384
    float* katt    = ws + 20480;               // 128
    bf16*  w1b     = (bf16*)(ws + 20736);      // 73728 bf16 -> 36864 f
    bf16*  wfinb   = (bf16*)(ws + 57600);      // 2359296 bf16 -> 1179648 f
    bf16*  t0b     = (bf16*)(ws + 1237248);    // 16777216 bf16 -> 8388608 f
    float* t1      = ws + 9625856;             // 7872512   (32,64,62,62)
    float* t2      = ws + 17498368;            // 1843200   (32,64,30,30)
    float* t3      = ws + 19341568;            // 401408    (32,64,14,14)
    // total ~19.75M floats = 79 MB

    // K1: watermark embedding MLP
    k_wm_embed<<<32, 128, 0, stream>>>(wm, wm_w1, wm_b1, wm_w2, wm_b2, wm_coff);

    // K2: pool + modulate -> NHWC bf16
    k_pool_nhwc<<<dim3(64, 32), 256, 0, stream>>>(x, wm_coff, t0b);

    // Kw: tower conv1 weights -> bf16 [tap][co][cin]
    k_w1b<<<288, 256, 0, stream>>>(tr_w1, w1b);

    // K3: MFMA conv1 128->64 s1 p0 (64x64 -> 62x62), bias+lrelu, fp32 NCHW out
    k_conv_mfma<0, false, false, true, true, false><<<dim3(62, 1, 32), 256, 0, stream>>>(
        (const void*)t0b, w1b, tr_b1, t1, 64, 64, 62, 62);

    // K4: conv2 64->64 s2 (62 -> 30), lrelu
    k_conv3x3_s2<true><<<dim3(64, 32), 256, 64 * 9 * 4, stream>>>(
        t1, tr_w2, tr_b2, t2, 64, 62, 62, 30, 30);

    // K5: conv3 64->64 s2 (30 -> 14), lrelu
    k_conv3x3_s2<true><<<dim3(64, 32), 256, 64 * 9 * 4, stream>>>(
        t2, tr_w3, tr_b3, t3, 64, 30, 30, 14, 14);

    // K6: fused heads
    HeadPtrs hp;
    hp.w[0] = t1_w; hp.w[1] = t2_w; hp.w[2] = t3_w; hp.w[3] = t4_w; hp.w[4] = att_cw;
    hp.b[0] = t1_b; hp.b[1] = t2_b; hp.b[2] = t3_b; hp.b[3] = t4_b; hp.b[4] = att_cb;
    k_heads_fused<<<32, 256, 0, stream>>>(t3, hp, att_fw, att_fb, agg, katt);

    // K7: synthesize per-sample bf16 weights [b][tap][co][cin], wm_coff folded
    k_combine<<<9216, 256, 0, stream>>>(expert_w, agg, katt, wm_coff, wfinb);

    // K8: MFMA per-sample conv on RAW x (float4 staging), pad 1, y-band XCD swizzle
    k_conv_mfma<1, true, true, false, false, true><<<dim3(128, 2, 32), 256, 0, stream>>>(
        (const void*)x, wfinb, nullptr, out, 128, 128, 128, 128);
}

// Round 5
// 668.765 us; speedup vs baseline: 6.2439x; 1.4111x over previous
//
#include <hip/hip_runtime.h>
#include <hip/hip_bf16.h>
#include <cstddef>
#include <cstdint>

typedef __bf16 bf16;
typedef __attribute__((ext_vector_type(8))) __bf16 bf16x8;
typedef __attribute__((ext_vector_type(4))) __bf16 bf16x4;
typedef __attribute__((ext_vector_type(4))) float f32x4;

// ---------------------------------------------------------------------------
// Pipeline:
//  K1  wm embedding MLP -> wm_coff (32,128)                    [fp32]
//  Kx  x NCHW fp32 -> xb NHWC bf16 (32,128,128,128)            [LDS transpose]
//  K2  pool2x2(xb) + modulate -> t0b NHWC bf16 (32,64,64,128)
//  Kw1 tr_w1 -> w1b bf16 [9][64co][128cin]
//  Kw2 tr_w2 -> w2b bf16 [9][64co][64cin]
//  K3  MFMA conv 128->64 s1 p0 +bias+lrelu -> t1b NHWC bf16 (32,62,62,64)
//  K4  MFMA conv 64->64 s2 p0 +bias+lrelu -> t2 fp32 NCHW (32,64,30,30)
//  K5  conv 64->64 s2 + lrelu -> t3 fp32 NCHW (32,64,14,14)   [fp32 scalar]
//  K6  fused heads (GAP trick) -> agg (32,4,128), katt (32,4)
//  K7  combine + fold wm_coff -> wfinb bf16 [32][9][64co][128cin]
//  K8  MFMA per-sample conv(xb, wfinb) p1 -> out fp32 NCHW (32,64,128,128)
// ---------------------------------------------------------------------------

__global__ void k_wm_embed(const float* __restrict__ wm, const float* __restrict__ w1,
                           const float* __restrict__ b1, const float* __restrict__ w2,
                           const float* __restrict__ b2, float* __restrict__ coff) {
    int b = blockIdx.x;      // 32
    int j = threadIdx.x;     // 128
    __shared__ float h[128];
    float acc = b1[j];
    for (int k = 0; k < 32; ++k) acc += wm[b * 32 + k] * w1[j * 32 + k];
    h[j] = acc >= 0.f ? acc : 0.2f * acc;   // slope 0.2
    __syncthreads();
    float acc2 = b2[j];
    for (int k = 0; k < 128; ++k) acc2 += h[k] * w2[j * 128 + k];
    coff[b * 128 + j] = acc2;
}

// x [b][c][y][x] fp32 -> xb [b][y][x][c] bf16, via 128x128 LDS tile per (b,y).
__global__ __launch_bounds__(256) void k_x2nhwc(const float* __restrict__ x,
                                                bf16* __restrict__ xb) {
    __shared__ bf16 t[128 * 128];   // [xp][c] slot-swizzled
    const int y = blockIdx.x, b = blockIdx.y;
    const float* xp0 = x + ((size_t)b << 21) + ((size_t)y << 7);
    for (int i = threadIdx.x; i < 16384; i += 256) {
        int c = i >> 7, xp = i & 127;                  // lanes sweep xp: coalesced
        float v = xp0[((size_t)c << 14) + xp];
        t[(xp << 7) + ((((c >> 3) ^ (xp & 15))) << 3) + (c & 7)] = (bf16)v;
    }
    __syncthreads();
    bf16* ob = xb + ((((size_t)b << 7) + y) << 14);
    for (int j = threadIdx.x; j < 2048; j += 256) {
        int xp = j >> 4, s = j & 15;
        *(bf16x8*)(ob + (xp << 7) + (s << 3)) =
            *(bf16x8*)(t + (xp << 7) + ((s ^ (xp & 15)) << 3));
    }
}

// t0b[b][y2][x2][c] = bf16( 0.25*coff[b,c]*(2x2 sum of xb) )
__global__ __launch_bounds__(256) void k_pool_nhwc(const bf16* __restrict__ xb,
                                                   const float* __restrict__ coff,
                                                   bf16* __restrict__ t0b) {
    __shared__ float cf[128];
    const int y2 = blockIdx.x, b = blockIdx.y;
    if (threadIdx.x < 128) cf[threadIdx.x] = 0.25f * coff[b * 128 + threadIdx.x];
    __syncthreads();
    const bf16* r0 = xb + ((((size_t)b << 7) + 2 * y2) << 14);
    const bf16* r1 = r0 + (1 << 14);
    for (int u = threadIdx.x; u < 1024; u += 256) {
        int s = u & 15, x2 = u >> 4;
        int o = (x2 << 8) + (s << 3);
        bf16x8 va = *(const bf16x8*)(r0 + o), vb = *(const bf16x8*)(r0 + o + 128);
        bf16x8 vc = *(const bf16x8*)(r1 + o), vd = *(const bf16x8*)(r1 + o + 128);
        bf16x8 pk;
#pragma unroll
        for (int j = 0; j < 8; ++j)
            pk[j] = (bf16)(((float)va[j] + (float)vb[j] + (float)vc[j] + (float)vd[j]) * cf[s * 8 + j]);
        *(bf16x8*)(t0b + ((((size_t)b * 64 + y2) * 64 + x2) << 7) + (s << 3)) = pk;
    }
}

// tr_w1 [64][128][3][3] fp32 -> w1b [tap][co][cin=128] bf16
__global__ void k_w1b(const float* __restrict__ w, bf16* __restrict__ o) {
    int i = blockIdx.x * 256 + threadIdx.x;     // 73728
    if (i >= 73728) return;
    int cin = i & 127, t2 = i >> 7, co = t2 & 63, tap = t2 >> 6;
    o[i] = (bf16)(w[((size_t)co * 128 + cin) * 9 + tap]);
}

// tr_w2 [64][64][3][3] fp32 -> w2b [tap][co][cin=64] bf16
__global__ void k_w2b(const float* __restrict__ w, bf16* __restrict__ o) {
    int i = blockIdx.x * 256 + threadIdx.x;     // 36864
    if (i >= 36864) return;
    int cin = i & 63, co = (i >> 6) & 63, tap = i >> 12;
    o[i] = (bf16)(w[((size_t)co * 64 + cin) * 9 + tap]);
}

// ---------------------------------------------------------------------------
// MFMA implicit-GEMM 3x3 conv, Cin=128 -> Cout=64, stride 1, NHWC bf16 src.
// Block: 64 co x 64 pos (one output row). 4 waves, each 32x32 (2x2 frags).
// LDS x-tile [3][66][128] bf16, 16B-slot XOR swizzle (slot ^ (col&15)).
// ---------------------------------------------------------------------------
template<int PAD, bool PER_BATCH_W, bool LRELU, bool HAS_BIAS, bool SWZY, bool NHWC_OUT>
__global__ __launch_bounds__(256, 3) void k_conv_mfma(
    const bf16* __restrict__ src, const bf16* __restrict__ wgt,
    const float* __restrict__ bias, void* __restrict__ outp,
    int H, int W, int Hout, int Wout)
{
    __shared__ bf16 xs[3 * 66 * 128];           // 50688 B
    const int tid = threadIdx.x;
    const int wid = tid >> 6, lane = tid & 63;
    const int b = blockIdx.z;
    const int x0 = blockIdx.y << 6;
    int bx = blockIdx.x;
    const int y0 = SWZY ? (((bx & 7) << 4) | (bx >> 3)) : bx;   // 16-row XCD bands

    // ---- stage x-tile -> LDS (vector 16B, swizzled source, linear-ish dest) ----
    const bf16* sb = src + (((size_t)b * H) * W << 7);
    for (int k = tid; k < 3 * 66 * 16; k += 256) {
        int r = k / 1056;
        int rem = k - r * 1056;
        int c = rem >> 4, sp = rem & 15;
        int ys = y0 - PAD + r, xsrc = x0 - PAD + c;
        bf16x8 v = {};
        if (ys >= 0 && ys < H && xsrc >= 0 && xsrc < W)
            v = *(const bf16x8*)(sb + (((size_t)ys * W + xsrc) << 7) + ((sp ^ (c & 15)) << 3));
        *(bf16x8*)(xs + (k << 3)) = v;
    }
    __syncthreads();

    // ---- K-loop: 9 taps x 4 cin-chunks, 4 MFMA each ----
    const bf16* wb = wgt + (PER_BATCH_W ? ((size_t)b * 9 * 64 * 128) : 0);
    const int co0 = (wid >> 1) << 5;             // 0 / 32
    const int p0  = (wid & 1) << 5;              // 0 / 32
    const int l15 = lane & 15, g = lane >> 4;
    const int arow0 = co0 + l15;
    const int aoff = g << 3;
    f32x4 acc[2][2] = {};

    for (int r = 0; r < 3; ++r) {
#pragma unroll
        for (int dx = 0; dx < 3; ++dx) {
            const bf16* wtap = wb + ((size_t)(r * 3 + dx) << 13);
            const int c0 = p0 + l15 + dx;
            const int rowbase = (r * 66 + c0) << 7;
            const int rowbase1 = (r * 66 + c0 + 16) << 7;
#pragma unroll
            for (int q = 0; q < 4; ++q) {
                bf16x8 a0 = *(const bf16x8*)(wtap + (arow0 << 7) + (q << 5) + aoff);
                bf16x8 a1 = *(const bf16x8*)(wtap + ((arow0 + 16) << 7) + (q << 5) + aoff);
                int sl = ((q << 2) + g) ^ (c0 & 15);
                bf16x8 b0 = *(const bf16x8*)(xs + rowbase + (sl << 3));
                bf16x8 b1 = *(const bf16x8*)(xs + rowbase1 + (sl << 3));
                acc[0][0] = __builtin_amdgcn_mfma_f32_16x16x32_bf16(a0, b0, acc[0][0], 0, 0, 0);
                acc[0][1] = __builtin_amdgcn_mfma_f32_16x16x32_bf16(a0, b1, acc[0][1], 0, 0, 0);
                acc[1][0] = __builtin_amdgcn_mfma_f32_16x16x32_bf16(a1, b0, acc[1][0], 0, 0, 0);
                acc[1][1] = __builtin_amdgcn_mfma_f32_16x16x32_bf16(a1, b1, acc[1][1], 0, 0, 0);
            }
        }
    }

    // ---- epilogue: col=lane&15 -> pos, row=(lane>>4)*4+reg -> co ----
#pragma unroll
    for (int m = 0; m < 2; ++m) {
#pragma unroll
        for (int n = 0; n < 2; ++n) {
            int xg = x0 + p0 + n * 16 + l15;
            if (xg < Wout) {
                if (NHWC_OUT) {
                    bf16x4 pk;
#pragma unroll
                    for (int reg = 0; reg < 4; ++reg) {
                        int co = co0 + m * 16 + (g << 2) + reg;
                        float v = acc[m][n][reg];
                        if (HAS_BIAS) v += bias[co];
                        if (LRELU) v = v >= 0.f ? v : 0.01f * v;
                        pk[reg] = (bf16)v;
                    }
                    *(bf16x4*)((bf16*)outp + ((((size_t)b * Hout + y0) * Wout + xg) << 6)
                               + co0 + m * 16 + (g << 2)) = pk;
                } else {
#pragma unroll
                    for (int reg = 0; reg < 4; ++reg) {
                        int co = co0 + m * 16 + (g << 2) + reg;
                        float v = acc[m][n][reg];
                        if (HAS_BIAS) v += bias[co];
                        if (LRELU) v = v >= 0.f ? v : 0.01f * v;
                        ((float*)outp)[(((size_t)b * 64 + co) * Hout + y0) * Wout + xg] = v;
                    }
                }
            }
        }
    }
}

// ---------------------------------------------------------------------------
// K4: MFMA conv 64cin->64co, k3, s2, p0. In t1b [b][62][62][64] bf16 NHWC,
// out t2 fp32 NCHW (32,64,30,30) + bias + lrelu.
// Even/odd input-column LDS planes make stride-2 B-fragments contiguous.
// Block = (y0, b): 4 waves x (16co x 32pos). LDS planes [2][3][33][64].
// ---------------------------------------------------------------------------
__global__ __launch_bounds__(256) void k_conv_s2_mfma(
    const bf16* __restrict__ t1b, const bf16* __restrict__ w2b,
    const float* __restrict__ bias, float* __restrict__ t2)
{
    __shared__ bf16 pl[2 * 3 * 33 * 64];        // E plane then O plane, 25344 B
    const int tid = threadIdx.x;
    const int wid = tid >> 6, lane = tid & 63;
    const int y0 = blockIdx.x, b = blockIdx.y;

    // stage 3 input rows (iy = 2*y0+r), split even/odd columns, slot-swizzled
    for (int k = tid; k < 1536; k += 256) {
        int sl = k & 7, xsc = (k >> 3) & 63, r = k >> 9;
        if (xsc < 62) {
            int iy = 2 * y0 + r;
            bf16x8 v = *(const bf16x8*)(t1b + (((size_t)b * 3844 + iy * 62 + xsc) << 6) + (sl << 3));
            int pcol = xsc >> 1;
            int dst = (xsc & 1) * 6336 + ((r * 33 + pcol) << 6) + ((sl ^ (pcol & 7)) << 3);
            *(bf16x8*)(pl + dst) = v;
        }
    }
    __syncthreads();

    const int co0 = wid << 4;                    // 16 co per wave
    const int l15 = lane & 15, g = lane >> 4;
    f32x4 acc[2] = {};

    for (int r = 0; r < 3; ++r) {
#pragma unroll
        for (int dx = 0; dx < 3; ++dx) {
            const bf16* wt = w2b + ((size_t)(r * 3 + dx) << 12);
            const int pbase = (dx == 1) ? 6336 : 0;
            const int cadd = (dx == 2) ? 1 : 0;
#pragma unroll
            for (int q = 0; q < 2; ++q) {
                bf16x8 a = *(const bf16x8*)(wt + ((co0 + l15) << 6) + (q << 5) + (g << 3));
#pragma unroll
                for (int n = 0; n < 2; ++n) {
                    int col = (n << 4) + l15 + cadd;
                    int sl = ((q << 2) + g) ^ (col & 7);
                    bf16x8 bf = *(const bf16x8*)(pl + pbase + ((r * 33 + col) << 6) + (sl << 3));
                    acc[n] = __builtin_amdgcn_mfma_f32_16x16x32_bf16(a, bf, acc[n], 0, 0, 0);
                }
            }
        }
    }

#pragma unroll
    for (int n = 0; n < 2; ++n) {
        int pos = (n << 4) + l15;
        if (pos < 30) {
#pragma unroll
            for (int reg = 0; reg < 4; ++reg) {
                int co = co0 + (g << 2) + reg;
                float v = acc[n][reg] + bias[co];
                v = v >= 0.f ? v : 0.01f * v;
                t2[(((size_t)b * 64 + co) * 30 + y0) * 30 + pos] = v;
            }
        }
    }
}

// Small 3x3 stride-2 pad-0 fp32 conv (K5 only): one block per (co, b).
template<bool LRELU>
__global__ __launch_bounds__(256) void k_conv3x3_s2(
    const float* __restrict__ in, const float* __restrict__ w,
    const float* __restrict__ bias, float* __restrict__ out,
    int Cin, int Hin, int Win, int Hout, int Wout)
{
    const int co = blockIdx.x, Cout = gridDim.x, b = blockIdx.y;
    extern __shared__ float wl[];   // Cin*9
    for (int i = threadIdx.x; i < Cin * 9; i += 256) wl[i] = w[(size_t)co * Cin * 9 + i];
    __syncthreads();
    const float* ib = in + (size_t)b * Cin * Hin * Win;
    const int npix = Hout * Wout;
    const float bv = bias[co];
    for (int p = threadIdx.x; p < npix; p += 256) {
        int oyr = p / Wout, oxr = p - oyr * Wout;
        int iy0 = oyr * 2, ix0 = oxr * 2;
        float acc = bv;
        for (int ci = 0; ci < Cin; ++ci) {
            const float* xp = ib + ((size_t)ci * Hin + iy0) * Win + ix0;
            const float* wp = wl + ci * 9;
            acc += xp[0]*wp[0] + xp[1]*wp[1] + xp[2]*wp[2]
                 + xp[Win]*wp[3] + xp[Win+1]*wp[4] + xp[Win+2]*wp[5]
                 + xp[2*Win]*wp[6] + xp[2*Win+1]*wp[7] + xp[2*Win+2]*wp[8];
        }
        out[((size_t)b * Cout + co) * npix + p] = LRELU ? (acc >= 0.f ? acc : 0.01f * acc) : acc;
    }
}

// Fused heads: mean_pos(conv(t,w)) = (1/36) sum_{cin,k} w[co,cin,k]*S[cin,k]
struct HeadPtrs { const float* w[5]; const float* b[5]; };

__global__ __launch_bounds__(256) void k_heads_fused(
    const float* __restrict__ t3, HeadPtrs hp,
    const float* __restrict__ att_fw, const float* __restrict__ att_fb,
    float* __restrict__ agg, float* __restrict__ katt)
{
    int b = blockIdx.x;
    __shared__ float S[576];
    __shared__ float ah[128];
    const float* tb = t3 + (size_t)b * 64 * 196;
    for (int i = threadIdx.x; i < 576; i += 256) {
        int ci = i / 9, k = i - ci * 9, kh = k / 3, kw = k - kh * 3;
        const float* tp = tb + ci * 196 + kh * 14 + kw;
        float s = 0.f;
#pragma unroll
        for (int oy = 0; oy < 6; ++oy)
#pragma unroll
            for (int ox = 0; ox < 6; ++ox) s += tp[oy * 28 + ox * 2];
        S[i] = s;
    }
    __syncthreads();
    for (int j = threadIdx.x; j < 640; j += 256) {
        int h = j >> 7, co = j & 127;
        const float* wp = hp.w[h] + (size_t)co * 576;
        float acc = 0.f;
        for (int k = 0; k < 576; ++k) acc += wp[k] * S[k];
        float v = acc * (1.f / 36.f) + hp.b[h][co];
        if (h < 4) agg[((size_t)b * 4 + h) * 128 + co] = v;
        else       ah[co] = v >= 0.f ? v : 0.01f * v;
    }
    __syncthreads();
    if (threadIdx.x < 4) {
        int e = threadIdx.x;
        float acc = att_fb[e];
        for (int j = 0; j < 128; ++j) acc += ah[j] * att_fw[e * 128 + j];
        katt[b * 4 + e] = acc;
    }
}

// wfinb[b][tap][co][cin] = bf16( coff[b,cin] * sum_e katt[b,e]*agg[b,e,cin]*expert_w[e,co,cin,tap] )
__global__ __launch_bounds__(256) void k_combine(
    const float* __restrict__ expert_w, const float* __restrict__ agg,
    const float* __restrict__ katt, const float* __restrict__ coff,
    bf16* __restrict__ wfinb)
{
    int i = blockIdx.x * 256 + threadIdx.x;   // 32*9*64*128 = 2359296 exact
    int cin = i & 127;
    int co  = (i >> 7) & 63;
    int tap = (i >> 13) % 9;
    int b   = i / (9 << 13);
    float s = 0.f;
#pragma unroll
    for (int e = 0; e < 4; ++e)
        s += katt[b * 4 + e] * agg[((size_t)b * 4 + e) * 128 + cin]
           * expert_w[(((size_t)e * 64 + co) * 128 + cin) * 9 + tap];
    wfinb[i] = (bf16)(s * coff[b * 128 + cin]);
}

extern "C" void kernel_launch(void* const* d_in, const int* in_sizes, int n_in,
                              void* d_out, int out_size, void* d_ws, size_t ws_size,
                              hipStream_t stream) {
    const float* x      = (const float*)d_in[0];
    const float* wm     = (const float*)d_in[1];
    const float* wm_w1  = (const float*)d_in[2];
    const float* wm_b1  = (const float*)d_in[3];
    const float* wm_w2  = (const float*)d_in[4];
    const float* wm_b2  = (const float*)d_in[5];
    const float* tr_w1  = (const float*)d_in[6];
    const float* tr_b1  = (const float*)d_in[7];
    const float* tr_w2  = (const float*)d_in[8];
    const float* tr_b2  = (const float*)d_in[9];
    const float* tr_w3  = (const float*)d_in[10];
    const float* tr_b3  = (const float*)d_in[11];
    const float* t1_w   = (const float*)d_in[12];
    const float* t1_b   = (const float*)d_in[13];
    const float* t2_w   = (const float*)d_in[14];
    const float* t2_b   = (const float*)d_in[15];
    const float* t3_w   = (const float*)d_in[16];
    const float* t3_b   = (const float*)d_in[17];
    const float* t4_w   = (const float*)d_in[18];
    const float* t4_b   = (const float*)d_in[19];
    const float* att_cw = (const float*)d_in[20];
    const float* att_cb = (const float*)d_in[21];
    const float* att_fw = (const float*)d_in[22];
    const float* att_fb = (const float*)d_in[23];
    const float* expert_w = (const float*)d_in[24];
    float* out = (float*)d_out;

    // Workspace layout (float offsets; all 16B-aligned)
    float* ws = (float*)d_ws;
    float* wm_coff = ws;                       // 4096
    float* agg     = ws + 4096;                // 16384
    float* katt    = ws + 20480;               // 128
    bf16*  w1b     = (bf16*)(ws + 20736);      // 73728 bf16
    bf16*  w2b     = (bf16*)(ws + 57600);      // 36864 bf16
    bf16*  wfinb   = (bf16*)(ws + 76032);      // 2359296 bf16
    bf16*  xb      = (bf16*)(ws + 1255680);    // 67108864 bf16 (32,128,128,128)
    bf16*  t0b     = (bf16*)(ws + 34810112);   // 16777216 bf16 (32,64,64,128)
    bf16*  t1b     = (bf16*)(ws + 43198720);   // 7872512 bf16  (32,62,62,64)
    float* t2      = ws + 47134976;            // 1843200       (32,64,30,30)
    float* t3      = ws + 48978176;            // 401408        (32,64,14,14)
    // total 49379584 floats = ~198 MB

    // K1: watermark embedding MLP
    k_wm_embed<<<32, 128, 0, stream>>>(wm, wm_w1, wm_b1, wm_w2, wm_b2, wm_coff);

    // Kx: x -> NHWC bf16
    k_x2nhwc<<<dim3(128, 32), 256, 0, stream>>>(x, xb);

    // K2: pool + modulate -> t0b
    k_pool_nhwc<<<dim3(64, 32), 256, 0, stream>>>(xb, wm_coff, t0b);

    // Kw: weight repacks
    k_w1b<<<288, 256, 0, stream>>>(tr_w1, w1b);
    k_w2b<<<144, 256, 0, stream>>>(tr_w2, w2b);

    // K3: MFMA conv1 128->64 s1 p0 (64x64 -> 62x62), bias+lrelu, NHWC bf16 out
    k_conv_mfma<0, false, true, true, false, true><<<dim3(62, 1, 32), 256, 0, stream>>>(
        t0b, w1b, tr_b1, (void*)t1b, 64, 64, 62, 62);

    // K4: MFMA conv2 64->64 s2 (62 -> 30), bias+lrelu, fp32 NCHW out
    k_conv_s2_mfma<<<dim3(30, 32), 256, 0, stream>>>(t1b, w2b, tr_b2, t2);

    // K5: conv3 64->64 s2 (30 -> 14), lrelu
    k_conv3x3_s2<true><<<dim3(64, 32), 256, 64 * 9 * 4, stream>>>(
        t2, tr_w3, tr_b3, t3, 64, 30, 30, 14, 14);

    // K6: fused heads
    HeadPtrs hp;
    hp.w[0] = t1_w; hp.w[1] = t2_w; hp.w[2] = t3_w; hp.w[3] = t4_w; hp.w[4] = att_cw;
    hp.b[0] = t1_b; hp.b[1] = t2_b; hp.b[2] = t3_b; hp.b[3] = t4_b; hp.b[4] = att_cb;
    k_heads_fused<<<32, 256, 0, stream>>>(t3, hp, att_fw, att_fb, agg, katt);

    // K7: synthesize per-sample bf16 weights [b][tap][co][cin], wm_coff folded
    k_combine<<<9216, 256, 0, stream>>>(expert_w, agg, katt, wm_coff, wfinb);

    // K8: MFMA per-sample conv on xb, pad 1, y-band XCD swizzle, fp32 NCHW out
    k_conv_mfma<1, true, false, false, true, false><<<dim3(128, 2, 32), 256, 0, stream>>>(
        xb, wfinb, nullptr, (void*)out, 128, 128, 128, 128);
}

// Round 6
// 649.075 us; speedup vs baseline: 6.4333x; 1.0303x over previous
//
#include <hip/hip_runtime.h>
#include <hip/hip_bf16.h>
#include <cstddef>
#include <cstdint>

typedef __bf16 bf16;
typedef __attribute__((ext_vector_type(8))) __bf16 bf16x8;
typedef __attribute__((ext_vector_type(4))) __bf16 bf16x4;
typedef __attribute__((ext_vector_type(4))) float f32x4;

// ---------------------------------------------------------------------------
// Pipeline:
//  K1  wm embedding MLP -> wm_coff (32,128)                    [fp32]
//  Kxp x NCHW fp32 -> xb NHWC bf16 + pooled/modulated t0b      [fused]
//  Kw1 tr_w1 -> w1b bf16 [9][64co][128cin]
//  Kw2 tr_w2 -> w2b bf16 [9][64co][64cin]
//  K3  MFMA conv 128->64 s1 p0 +bias+lrelu -> t1b NHWC bf16 (32,62,62,64)
//  K4  MFMA conv 64->64 s2 p0 +bias+lrelu -> t2 fp32 NCHW (32,64,30,30)
//  K5  conv 64->64 s2 + lrelu -> t3 fp32 NCHW (32,64,14,14)   [fp32 scalar]
//  K6  fused heads (GAP trick) -> agg (32,4,128), katt (32,4)
//  K7  combine + fold wm_coff -> wfinb bf16 [32][9][64co][128cin]
//  K8  MFMA per-sample conv(xb, wfinb) p1 -> out fp32 NCHW (32,64,128,128)
// Conv template: 512 thr / 8 waves (16co x 32pos each) for latency hiding.
// ---------------------------------------------------------------------------

__global__ void k_wm_embed(const float* __restrict__ wm, const float* __restrict__ w1,
                           const float* __restrict__ b1, const float* __restrict__ w2,
                           const float* __restrict__ b2, float* __restrict__ coff) {
    int b = blockIdx.x;      // 32
    int j = threadIdx.x;     // 128
    __shared__ float h[128];
    float acc = b1[j];
    for (int k = 0; k < 32; ++k) acc += wm[b * 32 + k] * w1[j * 32 + k];
    h[j] = acc >= 0.f ? acc : 0.2f * acc;   // slope 0.2
    __syncthreads();
    float acc2 = b2[j];
    for (int k = 0; k < 128; ++k) acc2 += h[k] * w2[j * 128 + k];
    coff[b * 128 + j] = acc2;
}

// Fused: x [b][c][y][x] fp32 -> xb [b][y][x][c] bf16 (row pair) AND
// t0b[b][y2][x2][c] = bf16(0.25*coff[b,c]*(2x2 sum)) for that row pair.
__global__ __launch_bounds__(256) void k_x2nhwc_pool(
    const float* __restrict__ x, const float* __restrict__ coff,
    bf16* __restrict__ xb, bf16* __restrict__ t0b)
{
    __shared__ bf16 t[2][128 * 128];     // 64 KB, [row][xp][c] slot-swizzled
    __shared__ float cf[128];
    const int y2 = blockIdx.x, b = blockIdx.y;
    if (threadIdx.x < 128) cf[threadIdx.x] = 0.25f * coff[b * 128 + threadIdx.x];
    const float* xp0 = x + ((size_t)b << 21) + ((size_t)(2 * y2) << 7);
    for (int i = threadIdx.x; i < 32768; i += 256) {
        int row = i >> 14, j = i & 16383;
        int c = j >> 7, xp = j & 127;                  // lanes sweep xp: coalesced
        float v = xp0[((size_t)c << 14) + (row << 7) + xp];
        t[row][(xp << 7) + (((c >> 3) ^ (xp & 15)) << 3) + (c & 7)] = (bf16)v;
    }
    __syncthreads();
    bf16* ob = xb + ((((size_t)b << 7) + 2 * y2) << 14);
    for (int j = threadIdx.x; j < 4096; j += 256) {
        int row = j >> 11, u = j & 2047;
        int xp = u >> 4, s = u & 15;
        *(bf16x8*)(ob + (row << 14) + (xp << 7) + (s << 3)) =
            *(bf16x8*)(t[row] + (xp << 7) + ((s ^ (xp & 15)) << 3));
    }
    bf16* tb = t0b + (((size_t)b * 64 + y2) << 13);    // row y2: 64 x2 * 128 c
    for (int u = threadIdx.x; u < 1024; u += 256) {
        int s = u & 15, x2 = u >> 4;
        int xc0 = 2 * x2, xc1 = 2 * x2 + 1;
        bf16x8 va = *(bf16x8*)(t[0] + (xc0 << 7) + ((s ^ (xc0 & 15)) << 3));
        bf16x8 vb = *(bf16x8*)(t[0] + (xc1 << 7) + ((s ^ (xc1 & 15)) << 3));
        bf16x8 vc = *(bf16x8*)(t[1] + (xc0 << 7) + ((s ^ (xc0 & 15)) << 3));
        bf16x8 vd = *(bf16x8*)(t[1] + (xc1 << 7) + ((s ^ (xc1 & 15)) << 3));
        bf16x8 pk;
#pragma unroll
        for (int j = 0; j < 8; ++j)
            pk[j] = (bf16)(((float)va[j] + (float)vb[j] + (float)vc[j] + (float)vd[j]) * cf[s * 8 + j]);
        *(bf16x8*)(tb + (x2 << 7) + (s << 3)) = pk;
    }
}

// tr_w1 [64][128][3][3] fp32 -> w1b [tap][co][cin=128] bf16
__global__ void k_w1b(const float* __restrict__ w, bf16* __restrict__ o) {
    int i = blockIdx.x * 256 + threadIdx.x;     // 73728
    if (i >= 73728) return;
    int cin = i & 127, t2 = i >> 7, co = t2 & 63, tap = t2 >> 6;
    o[i] = (bf16)(w[((size_t)co * 128 + cin) * 9 + tap]);
}

// tr_w2 [64][64][3][3] fp32 -> w2b [tap][co][cin=64] bf16
__global__ void k_w2b(const float* __restrict__ w, bf16* __restrict__ o) {
    int i = blockIdx.x * 256 + threadIdx.x;     // 36864
    if (i >= 36864) return;
    int cin = i & 63, co = (i >> 6) & 63, tap = i >> 12;
    o[i] = (bf16)(w[((size_t)co * 64 + cin) * 9 + tap]);
}

// ---------------------------------------------------------------------------
// MFMA implicit-GEMM 3x3 conv, Cin=128 -> Cout=64, stride 1, NHWC bf16 src.
// Block: 64 co x 64 pos. 8 waves of (16co x 32pos); 1 A-load + 2 ds_read +
// 2 MFMA per unrolled step. LDS x-tile [3][66][128] bf16, slot^(col&15) swizzle.
// ---------------------------------------------------------------------------
template<int PAD, bool PER_BATCH_W, bool LRELU, bool HAS_BIAS, bool SWZY, bool NHWC_OUT>
__global__ __launch_bounds__(512, 8) void k_conv_mfma(
    const bf16* __restrict__ src, const bf16* __restrict__ wgt,
    const float* __restrict__ bias, void* __restrict__ outp,
    int H, int W, int Hout, int Wout)
{
    __shared__ bf16 xs[3 * 66 * 128];           // 50688 B
    const int tid = threadIdx.x;
    const int wid = tid >> 6, lane = tid & 63;
    const int b = blockIdx.z;
    const int x0 = blockIdx.y << 6;
    int bx = blockIdx.x;
    const int y0 = SWZY ? (((bx & 7) << 4) | (bx >> 3)) : bx;   // 16-row XCD bands

    // ---- stage x-tile -> LDS (vector 16B, swizzled source) ----
    const bf16* sb = src + (((size_t)b * H) * W << 7);
    for (int k = tid; k < 3 * 66 * 16; k += 512) {
        int r = k / 1056;
        int rem = k - r * 1056;
        int c = rem >> 4, sp = rem & 15;
        int ys = y0 - PAD + r, xsrc = x0 - PAD + c;
        bf16x8 v = {};
        if (ys >= 0 && ys < H && xsrc >= 0 && xsrc < W)
            v = *(const bf16x8*)(sb + (((size_t)ys * W + xsrc) << 7) + ((sp ^ (c & 15)) << 3));
        *(bf16x8*)(xs + (k << 3)) = v;
    }
    __syncthreads();

    // ---- K-loop: 9 taps x 4 cin-chunks, 2 MFMA each ----
    const bf16* wb = wgt + (PER_BATCH_W ? ((size_t)b * 9 * 64 * 128) : 0);
    const int co0 = (wid >> 1) << 4;             // 0,16,32,48
    const int p0  = (wid & 1) << 5;              // 0,32
    const int l15 = lane & 15, g = lane >> 4;
    const int arow = co0 + l15;
    const int aoff = g << 3;
    f32x4 acc[2] = {};

    for (int r = 0; r < 3; ++r) {
#pragma unroll
        for (int dx = 0; dx < 3; ++dx) {
            const bf16* wtap = wb + ((size_t)(r * 3 + dx) << 13);
            const int c0 = p0 + l15 + dx;
            const int rowbase = (r * 66 + c0) << 7;
            const int rowbase1 = (r * 66 + c0 + 16) << 7;
#pragma unroll
            for (int q = 0; q < 4; ++q) {
                bf16x8 a = *(const bf16x8*)(wtap + (arow << 7) + (q << 5) + aoff);
                int sl = ((q << 2) + g) ^ (c0 & 15);
                bf16x8 b0 = *(const bf16x8*)(xs + rowbase + (sl << 3));
                bf16x8 b1 = *(const bf16x8*)(xs + rowbase1 + (sl << 3));
                acc[0] = __builtin_amdgcn_mfma_f32_16x16x32_bf16(a, b0, acc[0], 0, 0, 0);
                acc[1] = __builtin_amdgcn_mfma_f32_16x16x32_bf16(a, b1, acc[1], 0, 0, 0);
            }
        }
    }

    // ---- epilogue: col=lane&15 -> pos, row=(lane>>4)*4+reg -> co ----
#pragma unroll
    for (int n = 0; n < 2; ++n) {
        int xg = x0 + p0 + n * 16 + l15;
        if (xg < Wout) {
            if (NHWC_OUT) {
                bf16x4 pk;
#pragma unroll
                for (int reg = 0; reg < 4; ++reg) {
                    int co = co0 + (g << 2) + reg;
                    float v = acc[n][reg];
                    if (HAS_BIAS) v += bias[co];
                    if (LRELU) v = v >= 0.f ? v : 0.01f * v;
                    pk[reg] = (bf16)v;
                }
                *(bf16x4*)((bf16*)outp + ((((size_t)b * Hout + y0) * Wout + xg) << 6)
                           + co0 + (g << 2)) = pk;
            } else {
#pragma unroll
                for (int reg = 0; reg < 4; ++reg) {
                    int co = co0 + (g << 2) + reg;
                    float v = acc[n][reg];
                    if (HAS_BIAS) v += bias[co];
                    if (LRELU) v = v >= 0.f ? v : 0.01f * v;
                    ((float*)outp)[(((size_t)b * 64 + co) * Hout + y0) * Wout + xg] = v;
                }
            }
        }
    }
}

// ---------------------------------------------------------------------------
// K4: MFMA conv 64cin->64co, k3, s2, p0. In t1b [b][62][62][64] bf16 NHWC,
// out t2 fp32 NCHW (32,64,30,30) + bias + lrelu.
// ---------------------------------------------------------------------------
__global__ __launch_bounds__(256) void k_conv_s2_mfma(
    const bf16* __restrict__ t1b, const bf16* __restrict__ w2b,
    const float* __restrict__ bias, float* __restrict__ t2)
{
    __shared__ bf16 pl[2 * 3 * 33 * 64];        // E plane then O plane, 25344 B
    const int tid = threadIdx.x;
    const int wid = tid >> 6, lane = tid & 63;
    const int y0 = blockIdx.x, b = blockIdx.y;

    for (int k = tid; k < 1536; k += 256) {
        int sl = k & 7, xsc = (k >> 3) & 63, r = k >> 9;
        if (xsc < 62) {
            int iy = 2 * y0 + r;
            bf16x8 v = *(const bf16x8*)(t1b + (((size_t)b * 3844 + iy * 62 + xsc) << 6) + (sl << 3));
            int pcol = xsc >> 1;
            int dst = (xsc & 1) * 6336 + ((r * 33 + pcol) << 6) + ((sl ^ (pcol & 7)) << 3);
            *(bf16x8*)(pl + dst) = v;
        }
    }
    __syncthreads();

    const int co0 = wid << 4;
    const int l15 = lane & 15, g = lane >> 4;
    f32x4 acc[2] = {};

    for (int r = 0; r < 3; ++r) {
#pragma unroll
        for (int dx = 0; dx < 3; ++dx) {
            const bf16* wt = w2b + ((size_t)(r * 3 + dx) << 12);
            const int pbase = (dx == 1) ? 6336 : 0;
            const int cadd = (dx == 2) ? 1 : 0;
#pragma unroll
            for (int q = 0; q < 2; ++q) {
                bf16x8 a = *(const bf16x8*)(wt + ((co0 + l15) << 6) + (q << 5) + (g << 3));
#pragma unroll
                for (int n = 0; n < 2; ++n) {
                    int col = (n << 4) + l15 + cadd;
                    int sl = ((q << 2) + g) ^ (col & 7);
                    bf16x8 bf = *(const bf16x8*)(pl + pbase + ((r * 33 + col) << 6) + (sl << 3));
                    acc[n] = __builtin_amdgcn_mfma_f32_16x16x32_bf16(a, bf, acc[n], 0, 0, 0);
                }
            }
        }
    }

#pragma unroll
    for (int n = 0; n < 2; ++n) {
        int pos = (n << 4) + l15;
        if (pos < 30) {
#pragma unroll
            for (int reg = 0; reg < 4; ++reg) {
                int co = co0 + (g << 2) + reg;
                float v = acc[n][reg] + bias[co];
                v = v >= 0.f ? v : 0.01f * v;
                t2[(((size_t)b * 64 + co) * 30 + y0) * 30 + pos] = v;
            }
        }
    }
}

// Small 3x3 stride-2 pad-0 fp32 conv (K5 only): one block per (co, b).
template<bool LRELU>
__global__ __launch_bounds__(256) void k_conv3x3_s2(
    const float* __restrict__ in, const float* __restrict__ w,
    const float* __restrict__ bias, float* __restrict__ out,
    int Cin, int Hin, int Win, int Hout, int Wout)
{
    const int co = blockIdx.x, Cout = gridDim.x, b = blockIdx.y;
    extern __shared__ float wl[];   // Cin*9
    for (int i = threadIdx.x; i < Cin * 9; i += 256) wl[i] = w[(size_t)co * Cin * 9 + i];
    __syncthreads();
    const float* ib = in + (size_t)b * Cin * Hin * Win;
    const int npix = Hout * Wout;
    const float bv = bias[co];
    for (int p = threadIdx.x; p < npix; p += 256) {
        int oyr = p / Wout, oxr = p - oyr * Wout;
        int iy0 = oyr * 2, ix0 = oxr * 2;
        float acc = bv;
        for (int ci = 0; ci < Cin; ++ci) {
            const float* xp = ib + ((size_t)ci * Hin + iy0) * Win + ix0;
            const float* wp = wl + ci * 9;
            acc += xp[0]*wp[0] + xp[1]*wp[1] + xp[2]*wp[2]
                 + xp[Win]*wp[3] + xp[Win+1]*wp[4] + xp[Win+2]*wp[5]
                 + xp[2*Win]*wp[6] + xp[2*Win+1]*wp[7] + xp[2*Win+2]*wp[8];
        }
        out[((size_t)b * Cout + co) * npix + p] = LRELU ? (acc >= 0.f ? acc : 0.01f * acc) : acc;
    }
}

// Fused heads: mean_pos(conv(t,w)) = (1/36) sum_{cin,k} w[co,cin,k]*S[cin,k]
struct HeadPtrs { const float* w[5]; const float* b[5]; };

__global__ __launch_bounds__(256) void k_heads_fused(
    const float* __restrict__ t3, HeadPtrs hp,
    const float* __restrict__ att_fw, const float* __restrict__ att_fb,
    float* __restrict__ agg, float* __restrict__ katt)
{
    int b = blockIdx.x;
    __shared__ float S[576];
    __shared__ float ah[128];
    const float* tb = t3 + (size_t)b * 64 * 196;
    for (int i = threadIdx.x; i < 576; i += 256) {
        int ci = i / 9, k = i - ci * 9, kh = k / 3, kw = k - kh * 3;
        const float* tp = tb + ci * 196 + kh * 14 + kw;
        float s = 0.f;
#pragma unroll
        for (int oy = 0; oy < 6; ++oy)
#pragma unroll
            for (int ox = 0; ox < 6; ++ox) s += tp[oy * 28 + ox * 2];
        S[i] = s;
    }
    __syncthreads();
    for (int j = threadIdx.x; j < 640; j += 256) {
        int h = j >> 7, co = j & 127;
        const float* wp = hp.w[h] + (size_t)co * 576;
        float acc = 0.f;
        for (int k = 0; k < 576; ++k) acc += wp[k] * S[k];
        float v = acc * (1.f / 36.f) + hp.b[h][co];
        if (h < 4) agg[((size_t)b * 4 + h) * 128 + co] = v;
        else       ah[co] = v >= 0.f ? v : 0.01f * v;
    }
    __syncthreads();
    if (threadIdx.x < 4) {
        int e = threadIdx.x;
        float acc = att_fb[e];
        for (int j = 0; j < 128; ++j) acc += ah[j] * att_fw[e * 128 + j];
        katt[b * 4 + e] = acc;
    }
}

// wfinb[b][tap][co][cin] = bf16( coff[b,cin] * sum_e katt[b,e]*agg[b,e,cin]*expert_w[e,co,cin,tap] )
__global__ __launch_bounds__(256) void k_combine(
    const float* __restrict__ expert_w, const float* __restrict__ agg,
    const float* __restrict__ katt, const float* __restrict__ coff,
    bf16* __restrict__ wfinb)
{
    int i = blockIdx.x * 256 + threadIdx.x;   // 32*9*64*128 = 2359296 exact
    int cin = i & 127;
    int co  = (i >> 7) & 63;
    int tap = (i >> 13) % 9;
    int b   = i / (9 << 13);
    float s = 0.f;
#pragma unroll
    for (int e = 0; e < 4; ++e)
        s += katt[b * 4 + e] * agg[((size_t)b * 4 + e) * 128 + cin]
           * expert_w[(((size_t)e * 64 + co) * 128 + cin) * 9 + tap];
    wfinb[i] = (bf16)(s * coff[b * 128 + cin]);
}

extern "C" void kernel_launch(void* const* d_in, const int* in_sizes, int n_in,
                              void* d_out, int out_size, void* d_ws, size_t ws_size,
                              hipStream_t stream) {
    const float* x      = (const float*)d_in[0];
    const float* wm     = (const float*)d_in[1];
    const float* wm_w1  = (const float*)d_in[2];
    const float* wm_b1  = (const float*)d_in[3];
    const float* wm_w2  = (const float*)d_in[4];
    const float* wm_b2  = (const float*)d_in[5];
    const float* tr_w1  = (const float*)d_in[6];
    const float* tr_b1  = (const float*)d_in[7];
    const float* tr_w2  = (const float*)d_in[8];
    const float* tr_b2  = (const float*)d_in[9];
    const float* tr_w3  = (const float*)d_in[10];
    const float* tr_b3  = (const float*)d_in[11];
    const float* t1_w   = (const float*)d_in[12];
    const float* t1_b   = (const float*)d_in[13];
    const float* t2_w   = (const float*)d_in[14];
    const float* t2_b   = (const float*)d_in[15];
    const float* t3_w   = (const float*)d_in[16];
    const float* t3_b   = (const float*)d_in[17];
    const float* t4_w   = (const float*)d_in[18];
    const float* t4_b   = (const float*)d_in[19];
    const float* att_cw = (const float*)d_in[20];
    const float* att_cb = (const float*)d_in[21];
    const float* att_fw = (const float*)d_in[22];
    const float* att_fb = (const float*)d_in[23];
    const float* expert_w = (const float*)d_in[24];
    float* out = (float*)d_out;

    // Workspace layout (float offsets; all 16B-aligned)
    float* ws = (float*)d_ws;
    float* wm_coff = ws;                       // 4096
    float* agg     = ws + 4096;                // 16384
    float* katt    = ws + 20480;               // 128
    bf16*  w1b     = (bf16*)(ws + 20736);      // 73728 bf16
    bf16*  w2b     = (bf16*)(ws + 57600);      // 36864 bf16
    bf16*  wfinb   = (bf16*)(ws + 76032);      // 2359296 bf16
    bf16*  xb      = (bf16*)(ws + 1255680);    // 67108864 bf16 (32,128,128,128)
    bf16*  t0b     = (bf16*)(ws + 34810112);   // 16777216 bf16 (32,64,64,128)
    bf16*  t1b     = (bf16*)(ws + 43198720);   // 7872512 bf16  (32,62,62,64)
    float* t2      = ws + 47134976;            // 1843200       (32,64,30,30)
    float* t3      = ws + 48978176;            // 401408        (32,64,14,14)
    // total 49379584 floats = ~198 MB

    // K1: watermark embedding MLP
    k_wm_embed<<<32, 128, 0, stream>>>(wm, wm_w1, wm_b1, wm_w2, wm_b2, wm_coff);

    // Kxp: x -> NHWC bf16 + pooled/modulated t0b (fused)
    k_x2nhwc_pool<<<dim3(64, 32), 256, 0, stream>>>(x, wm_coff, xb, t0b);

    // Kw: weight repacks
    k_w1b<<<288, 256, 0, stream>>>(tr_w1, w1b);
    k_w2b<<<144, 256, 0, stream>>>(tr_w2, w2b);

    // K3: MFMA conv1 128->64 s1 p0 (64x64 -> 62x62), bias+lrelu, NHWC bf16 out
    k_conv_mfma<0, false, true, true, false, true><<<dim3(62, 1, 32), 512, 0, stream>>>(
        t0b, w1b, tr_b1, (void*)t1b, 64, 64, 62, 62);

    // K4: MFMA conv2 64->64 s2 (62 -> 30), bias+lrelu, fp32 NCHW out
    k_conv_s2_mfma<<<dim3(30, 32), 256, 0, stream>>>(t1b, w2b, tr_b2, t2);

    // K5: conv3 64->64 s2 (30 -> 14), lrelu
    k_conv3x3_s2<true><<<dim3(64, 32), 256, 64 * 9 * 4, stream>>>(
        t2, tr_w3, tr_b3, t3, 64, 30, 30, 14, 14);

    // K6: fused heads
    HeadPtrs hp;
    hp.w[0] = t1_w; hp.w[1] = t2_w; hp.w[2] = t3_w; hp.w[3] = t4_w; hp.w[4] = att_cw;
    hp.b[0] = t1_b; hp.b[1] = t2_b; hp.b[2] = t3_b; hp.b[3] = t4_b; hp.b[4] = att_cb;
    k_heads_fused<<<32, 256, 0, stream>>>(t3, hp, att_fw, att_fb, agg, katt);

    // K7: synthesize per-sample bf16 weights [b][tap][co][cin], wm_coff folded
    k_combine<<<9216, 256, 0, stream>>>(expert_w, agg, katt, wm_coff, wfinb);

    // K8: MFMA per-sample conv on xb, pad 1, y-band XCD swizzle, fp32 NCHW out
    k_conv_mfma<1, true, false, false, true, false><<<dim3(128, 2, 32), 512, 0, stream>>>(
        xb, wfinb, nullptr, (void*)out, 128, 128, 128, 128);
}